// Round 1
// baseline (5369.231 us; speedup 1.0000x reference)
//
#include <hip/hip_runtime.h>
#include <hip/hip_bf16.h>

#define H 128

using bf16x8  = __attribute__((ext_vector_type(8))) short;  // 8 bf16 in 4 VGPRs
using floatx4 = __attribute__((ext_vector_type(4))) float;

static __device__ __forceinline__ short f2bf(float f) {
  union { float f; unsigned u; } v; v.f = f;
  unsigned r = v.u + 0x7fffu + ((v.u >> 16) & 1u);  // RNE
  return (short)(r >> 16);
}

// ---- degree counts (shared by both layers) ----
__global__ void count_edges(const int* __restrict__ src, const int* __restrict__ dst,
                            int E, float* __restrict__ cnt_s, float* __restrict__ cnt_d) {
  int e = blockIdx.x * blockDim.x + threadIdx.x;
  if (e >= E) return;
  unsafeAtomicAdd(&cnt_s[src[e]], 1.0f);
  unsafeAtomicAdd(&cnt_d[dst[e]], 1.0f);
}

__global__ void rcp_clamp(float* __restrict__ c, int n) {
  int i = blockIdx.x * blockDim.x + threadIdx.x;
  if (i < n) c[i] = 1.0f / fmaxf(c[i], 1.0f);
}

// ---- weight prep: bf16 convert, combine Wr pair and bias pair per (layer,type) ----
// set s = l*2 + t; t=0 -> post (rels 0,2), t=1 -> user (rels 1,3)
__global__ void prep_weights(const float* __restrict__ W_l, const float* __restrict__ b_l,
                             const float* __restrict__ W_r,
                             short* __restrict__ Wbf, float* __restrict__ bc) {
  int i = blockIdx.x * blockDim.x + threadIdx.x;
  if (i >= 4 * 16384) return;
  int s = i >> 14, e = i & 16383;
  int l = s >> 1, t = s & 1;
  int rA = t ? 1 : 0, rB = t ? 3 : 2;
  const float* WA = W_l + ((size_t)(l * 4 + rA) << 14);
  const float* WB = W_l + ((size_t)(l * 4 + rB) << 14);
  const float* RA = W_r + ((size_t)(l * 4 + rA) << 14);
  const float* RB = W_r + ((size_t)(l * 4 + rB) << 14);
  short* o = Wbf + (size_t)s * 3 * 16384;
  o[e]             = f2bf(WA[e]);
  o[16384 + e]     = f2bf(WB[e]);
  o[2 * 16384 + e] = f2bf(RA[e] + RB[e]);
  if (e < H) bc[s * H + e] = b_l[(l * 4 + rA) * H + e] + b_l[(l * 4 + rB) * H + e];
}

// ---- edge scatter: agg[dst] += x[src], 32 threads/edge, float4 gather ----
__global__ void scatter_add(const float4* __restrict__ x, const int* __restrict__ src,
                            const int* __restrict__ dst, float* __restrict__ agg, int E) {
  int t = blockIdx.x * blockDim.x + threadIdx.x;
  int e = t >> 5, c = t & 31;
  if (e >= E) return;
  int s = src[e], d = dst[e];
  float4 v = x[(size_t)s * 32 + c];
  float* o = agg + (size_t)d * H + c * 4;
  unsafeAtomicAdd(o + 0, v.x);
  unsafeAtomicAdd(o + 1, v.y);
  unsafeAtomicAdd(o + 2, v.z);
  unsafeAtomicAdd(o + 3, v.w);
}

// ---- fused SAGE transform: out = (aggV*rV)@WA.T + (aggL*rL)@WB.T + x@WR.T + b [, ReLU]
// bf16 MFMA 16x16x32; block = 4 waves, each wave does 16 rows x 128 cols.
// A frag: A[m=lane&15][k=quad*8+j]; B frag: B[k=quad*8+j][n=lane&15] = W[n][k];
// C/D: col=lane&15, row=quad*4+reg (HW-verified layouts).
__global__ __launch_bounds__(256) void fused_gemm(
    const float* __restrict__ aggV, const float* __restrict__ rV,
    const float* __restrict__ aggL, const float* __restrict__ rL,
    const float* __restrict__ x,
    const short* __restrict__ Wset,  // 3 * 128*128 bf16: WA, WB, WRcombined
    const float* __restrict__ bias,
    float* __restrict__ out, int N, int relu) {
  int wave = threadIdx.x >> 6;
  int lane = threadIdx.x & 63;
  int r = lane & 15, quad = lane >> 4;
  int row_base = blockIdx.x * 64 + wave * 16;
  int row = row_base + r;
  bool valid = row < N;
  int rowc = valid ? row : 0;

  float sc[3];
  sc[0] = valid ? rV[rowc] : 0.f;
  sc[1] = valid ? rL[rowc] : 0.f;
  sc[2] = valid ? 1.f : 0.f;
  const float* mats[3] = { aggV, aggL, x };

  floatx4 acc[8];
#pragma unroll
  for (int j = 0; j < 8; ++j) acc[j] = floatx4{0.f, 0.f, 0.f, 0.f};

#pragma unroll
  for (int m = 0; m < 3; ++m) {
    const float* A = mats[m] + (size_t)rowc * H + quad * 8;
    const short* W = Wset + (size_t)m * 16384 + quad * 8;
    float s = sc[m];
#pragma unroll
    for (int kk = 0; kk < H; kk += 32) {
      float4 a0 = *(const float4*)(A + kk);
      float4 a1 = *(const float4*)(A + kk + 4);
      bf16x8 af;
      af[0] = f2bf(a0.x * s); af[1] = f2bf(a0.y * s);
      af[2] = f2bf(a0.z * s); af[3] = f2bf(a0.w * s);
      af[4] = f2bf(a1.x * s); af[5] = f2bf(a1.y * s);
      af[6] = f2bf(a1.z * s); af[7] = f2bf(a1.w * s);
#pragma unroll
      for (int jt = 0; jt < 8; ++jt) {
        bf16x8 bf = *(const bf16x8*)(W + (jt * 16 + r) * H + kk);
        acc[jt] = __builtin_amdgcn_mfma_f32_16x16x32_bf16(af, bf, acc[jt], 0, 0, 0);
      }
    }
  }

#pragma unroll
  for (int jt = 0; jt < 8; ++jt) {
    int ocol = jt * 16 + r;
    float b = bias[ocol];
#pragma unroll
    for (int g = 0; g < 4; ++g) {
      int orow = row_base + quad * 4 + g;
      if (orow < N) {
        float v = acc[jt][g] + b;
        if (relu) v = fmaxf(v, 0.f);
        out[(size_t)orow * H + ocol] = v;
      }
    }
  }
}

extern "C" void kernel_launch(void* const* d_in, const int* in_sizes, int n_in,
                              void* d_out, int out_size, void* d_ws, size_t ws_size,
                              hipStream_t stream) {
  const float* emb_user = (const float*)d_in[0];
  const float* emb_post = (const float*)d_in[1];
  const float* W_l = (const float*)d_in[2];
  const float* b_l = (const float*)d_in[3];
  const float* W_r = (const float*)d_in[4];
  const int* ev_s = (const int*)d_in[5];
  const int* ev_d = (const int*)d_in[6];
  const int* el_s = (const int*)d_in[7];
  const int* el_d = (const int*)d_in[8];

  const int NU = in_sizes[0] / H;
  const int NP = in_sizes[1] / H;
  const int EV = in_sizes[5];
  const int EL = in_sizes[7];

  size_t NUH = (size_t)NU * H, NPH = (size_t)NP * H;
  float* ws   = (float*)d_ws;
  float* agg0 = ws;               // NP*H (reused for NU*H)
  float* agg1 = agg0 + NPH;       // NP*H
  float* xu1  = agg1 + NPH;       // NU*H  (layer-1 user out)
  float* xp1  = xu1 + NUH;        // NP*H  (layer-1 post out)
  float* rV_p = xp1 + NPH;        // NP  | contiguous count/rcnt block:
  float* rL_p = rV_p + NP;        // NP  |
  float* rV_u = rL_p + NP;        // NU  |
  float* rL_u = rV_u + NU;        // NU  |
  short* Wbf  = (short*)(rL_u + NU);               // 4 sets * 3 * 16384 bf16
  float* bc   = (float*)(Wbf + (size_t)4 * 3 * 16384);  // 4 * 128

  float* out_u_final = (float*)d_out;
  float* out_p_final = (float*)d_out + NUH;

  // degree counts -> reciprocal (once, reused by both layers)
  hipMemsetAsync(rV_p, 0, (size_t)(2 * NP + 2 * NU) * sizeof(float), stream);
  count_edges<<<(EV + 255) / 256, 256, 0, stream>>>(ev_s, ev_d, EV, rV_u, rV_p);
  count_edges<<<(EL + 255) / 256, 256, 0, stream>>>(el_s, el_d, EL, rL_u, rL_p);
  rcp_clamp<<<(2 * NP + 2 * NU + 255) / 256, 256, 0, stream>>>(rV_p, 2 * NP + 2 * NU);

  prep_weights<<<(4 * 16384 + 255) / 256, 256, 0, stream>>>(W_l, b_l, W_r, Wbf, bc);

  for (int l = 0; l < 2; ++l) {
    const float* xu_in = l ? xu1 : emb_user;
    const float* xp_in = l ? xp1 : emb_post;
    float* out_u = l ? out_u_final : xu1;
    float* out_p = l ? out_p_final : xp1;
    const short* Wpost = Wbf + (size_t)(l * 2 + 0) * 3 * 16384;
    const short* Wuser = Wbf + (size_t)(l * 2 + 1) * 3 * 16384;
    const float* bpost = bc + (l * 2 + 0) * H;
    const float* buser = bc + (l * 2 + 1) * H;

    // posts: aggregate users over viewed & liked, then fused transform
    hipMemsetAsync(agg0, 0, NPH * sizeof(float), stream);
    hipMemsetAsync(agg1, 0, NPH * sizeof(float), stream);
    scatter_add<<<(EV * 32 + 255) / 256, 256, 0, stream>>>((const float4*)xu_in, ev_s, ev_d, agg0, EV);
    scatter_add<<<(EL * 32 + 255) / 256, 256, 0, stream>>>((const float4*)xu_in, el_s, el_d, agg1, EL);
    fused_gemm<<<(NP + 63) / 64, 256, 0, stream>>>(agg0, rV_p, agg1, rL_p, xp_in,
                                                   Wpost, bpost, out_p, NP, l == 0);

    // users: aggregate posts over reversed edges, then fused transform
    hipMemsetAsync(agg0, 0, NUH * sizeof(float), stream);
    hipMemsetAsync(agg1, 0, NUH * sizeof(float), stream);
    scatter_add<<<(EV * 32 + 255) / 256, 256, 0, stream>>>((const float4*)xp_in, ev_d, ev_s, agg0, EV);
    scatter_add<<<(EL * 32 + 255) / 256, 256, 0, stream>>>((const float4*)xp_in, el_d, el_s, agg1, EL);
    fused_gemm<<<(NU + 63) / 64, 256, 0, stream>>>(agg0, rV_u, agg1, rL_u, xu_in,
                                                   Wuser, buser, out_u, NU, l == 0);
  }
}

// Round 2
// 1136.617 us; speedup vs baseline: 4.7239x; 4.7239x over previous
//
#include <hip/hip_runtime.h>
#include <hip/hip_bf16.h>

#define H 128

using bf16x8  = __attribute__((ext_vector_type(8))) short;  // 8 bf16 = 4 VGPRs
using floatx4 = __attribute__((ext_vector_type(4))) float;

static __device__ __forceinline__ short f2bf(float f) {
  union { float f; unsigned u; } v; v.f = f;
  unsigned r = v.u + 0x7fffu + ((v.u >> 16) & 1u);  // RNE
  return (short)(r >> 16);
}
static __device__ __forceinline__ float bf2f(short s) {
  union { unsigned u; float f; } v; v.u = ((unsigned)(unsigned short)s) << 16;
  return v.f;
}

// ---- degree counts (int) ----
__global__ void count_edges(const int* __restrict__ src, const int* __restrict__ dst,
                            int E, int* __restrict__ cnt_s, int* __restrict__ cnt_d) {
  int e = blockIdx.x * blockDim.x + threadIdx.x;
  if (e >= E) return;
  atomicAdd(&cnt_s[src[e]], 1);
  atomicAdd(&cnt_d[dst[e]], 1);
}

__global__ void rcp_from_cnt(const int* __restrict__ cnt, float* __restrict__ r, int n) {
  int i = blockIdx.x * blockDim.x + threadIdx.x;
  if (i < n) r[i] = 1.0f / fmaxf((float)cnt[i], 1.0f);
}

// ---- 3-kernel exclusive scan over 4 contiguous count arrays ----
__global__ __launch_bounds__(256) void scan_k1(const int* __restrict__ cnt, int* __restrict__ off,
                                               int* __restrict__ bsums, int4 starts, int4 lens) {
  int a = blockIdx.y;
  int start = ((const int*)&starts)[a];
  int len   = ((const int*)&lens)[a];
  int chunk = blockIdx.x * 1024;
  if (chunk >= len) return;
  const int* in = cnt + start;
  int* out = off + start;
  int tid = threadIdx.x;
  int base = chunk + tid * 4;
  int v[4];
#pragma unroll
  for (int j = 0; j < 4; ++j) v[j] = (base + j < len) ? in[base + j] : 0;
  int s = v[0] + v[1] + v[2] + v[3];
  __shared__ int lds[256];
  lds[tid] = s; __syncthreads();
  for (int o = 1; o < 256; o <<= 1) {
    int t = (tid >= o) ? lds[tid - o] : 0;
    __syncthreads();
    lds[tid] += t;
    __syncthreads();
  }
  int run = lds[tid] - s;  // exclusive prefix of this thread's 4
#pragma unroll
  for (int j = 0; j < 4; ++j) { if (base + j < len) out[base + j] = run; run += v[j]; }
  if (tid == 255) bsums[a * 256 + blockIdx.x] = lds[255];
}

__global__ __launch_bounds__(256) void scan_k2(int* __restrict__ bsums, int4 lens) {
  int a = blockIdx.x;
  int len = ((const int*)&lens)[a];
  int nb = (len + 1023) >> 10;
  int tid = threadIdx.x;
  int s = (tid < nb) ? bsums[a * 256 + tid] : 0;  // guard: slots >= nb are poisoned
  __shared__ int lds[256];
  lds[tid] = s; __syncthreads();
  for (int o = 1; o < 256; o <<= 1) {
    int t = (tid >= o) ? lds[tid - o] : 0;
    __syncthreads();
    lds[tid] += t;
    __syncthreads();
  }
  bsums[a * 256 + tid] = lds[tid] - s;
}

__global__ __launch_bounds__(256) void scan_k3(int* __restrict__ off, const int* __restrict__ bsums,
                                               int4 starts, int4 lens) {
  int a = blockIdx.y;
  int start = ((const int*)&starts)[a];
  int len   = ((const int*)&lens)[a];
  int chunk = blockIdx.x * 1024;
  if (chunk >= len) return;
  int add = bsums[a * 256 + blockIdx.x];
  int* out = off + start;
  int base = chunk + threadIdx.x * 4;
#pragma unroll
  for (int j = 0; j < 4; ++j) if (base + j < len) out[base + j] += add;
}

// ---- CSR fill (both directions of one relation) ----
__global__ void fill_csr(const int* __restrict__ src, const int* __restrict__ dst, int E,
                         const int* __restrict__ off_d, int* __restrict__ cur_d, int* __restrict__ sort_d,
                         const int* __restrict__ off_s, int* __restrict__ cur_s, int* __restrict__ sort_s) {
  int e = blockIdx.x * blockDim.x + threadIdx.x;
  if (e >= E) return;
  int s = src[e], d = dst[e];
  sort_d[off_d[d] + atomicAdd(&cur_d[d], 1)] = s;  // neighbors of dst node (src ids)
  sort_s[off_s[s] + atomicAdd(&cur_s[s], 1)] = d;  // neighbors of src node (dst ids)
}

// ---- fp32 -> bf16 streaming convert ----
__global__ void cvt_bf16(const float* __restrict__ in, short* __restrict__ out, int n) {
  int idx = (blockIdx.x * blockDim.x + threadIdx.x) * 4;
  if (idx >= n) return;
  float4 v = *(const float4*)(in + idx);
  short4 o = { f2bf(v.x), f2bf(v.y), f2bf(v.z), f2bf(v.w) };
  *(short4*)(out + idx) = o;
}

// ---- weight prep: bf16 convert, combine Wr pair and bias pair per (layer,type) ----
__global__ void prep_weights(const float* __restrict__ W_l, const float* __restrict__ b_l,
                             const float* __restrict__ W_r,
                             short* __restrict__ Wbf, float* __restrict__ bc) {
  int i = blockIdx.x * blockDim.x + threadIdx.x;
  if (i >= 4 * 16384) return;
  int s = i >> 14, e = i & 16383;
  int l = s >> 1, t = s & 1;
  int rA = t ? 1 : 0, rB = t ? 3 : 2;
  const float* WA = W_l + ((size_t)(l * 4 + rA) << 14);
  const float* WB = W_l + ((size_t)(l * 4 + rB) << 14);
  const float* RA = W_r + ((size_t)(l * 4 + rA) << 14);
  const float* RB = W_r + ((size_t)(l * 4 + rB) << 14);
  short* o = Wbf + (size_t)s * 3 * 16384;
  o[e]             = f2bf(WA[e]);
  o[16384 + e]     = f2bf(WB[e]);
  o[2 * 16384 + e] = f2bf(RA[e] + RB[e]);
  if (e < H) bc[s * H + e] = b_l[(l * 4 + rA) * H + e] + b_l[(l * 4 + rB) * H + e];
}

// ---- gather-based segment mean: 16 lanes per node, bf16x8 per lane, fp32 accum ----
__global__ __launch_bounds__(256) void aggregate(
    const bf16x8* __restrict__ xbf,
    const int* __restrict__ sV, const int* __restrict__ offV, const int* __restrict__ cntV,
    const float* __restrict__ rV,
    const int* __restrict__ sL, const int* __restrict__ offL, const int* __restrict__ cntL,
    const float* __restrict__ rL,
    bf16x8* __restrict__ mV, bf16x8* __restrict__ mL, int N) {
  int t = blockIdx.x * 256 + threadIdx.x;
  int node = t >> 4, c = t & 15;
  if (node >= N) return;
  float acc[8];
  {
    int o = offV[node], n = cntV[node];
#pragma unroll
    for (int j = 0; j < 8; ++j) acc[j] = 0.f;
    for (int i = o; i < o + n; ++i) {
      bf16x8 v = xbf[(size_t)sV[i] * 16 + c];
#pragma unroll
      for (int j = 0; j < 8; ++j) acc[j] += bf2f(v[j]);
    }
    float r = rV[node];
    bf16x8 w;
#pragma unroll
    for (int j = 0; j < 8; ++j) w[j] = f2bf(acc[j] * r);
    mV[(size_t)node * 16 + c] = w;
  }
  {
    int o = offL[node], n = cntL[node];
#pragma unroll
    for (int j = 0; j < 8; ++j) acc[j] = 0.f;
    for (int i = o; i < o + n; ++i) {
      bf16x8 v = xbf[(size_t)sL[i] * 16 + c];
#pragma unroll
      for (int j = 0; j < 8; ++j) acc[j] += bf2f(v[j]);
    }
    float r = rL[node];
    bf16x8 w;
#pragma unroll
    for (int j = 0; j < 8; ++j) w[j] = f2bf(acc[j] * r);
    mL[(size_t)node * 16 + c] = w;
  }
}

// ---- fused SAGE transform: out = mV@WA.T + mL@WB.T + x@WRc.T + b [, ReLU]
// bf16 MFMA 16x16x32; block = 4 waves; wave does 16 rows x 128 cols.
// A frag: A[m=lane&15][k=quad*8+j]; B frag: B[k][n=lane&15]=W[n][k]; C/D: col=lane&15, row=quad*4+reg.
__global__ __launch_bounds__(256) void fused_gemm(
    const short* __restrict__ mV, const short* __restrict__ mL, const short* __restrict__ xb,
    const short* __restrict__ Wset, const float* __restrict__ bias,
    float* __restrict__ out32, short* __restrict__ out16, int N, int relu) {
  int wave = threadIdx.x >> 6;
  int lane = threadIdx.x & 63;
  int r = lane & 15, quad = lane >> 4;
  int row_base = blockIdx.x * 64 + wave * 16;
  int row = row_base + r;
  int rowc = row < N ? row : 0;

  const short* mats[3] = { mV, mL, xb };
  floatx4 acc[8];
#pragma unroll
  for (int j = 0; j < 8; ++j) acc[j] = floatx4{0.f, 0.f, 0.f, 0.f};

#pragma unroll
  for (int m = 0; m < 3; ++m) {
    const short* A = mats[m] + (size_t)rowc * H + quad * 8;
    const short* W = Wset + (size_t)m * 16384 + quad * 8;
#pragma unroll
    for (int kk = 0; kk < H; kk += 32) {
      bf16x8 af = *(const bf16x8*)(A + kk);
#pragma unroll
      for (int jt = 0; jt < 8; ++jt) {
        bf16x8 bf = *(const bf16x8*)(W + (jt * 16 + r) * H + kk);
        acc[jt] = __builtin_amdgcn_mfma_f32_16x16x32_bf16(af, bf, acc[jt], 0, 0, 0);
      }
    }
  }

#pragma unroll
  for (int jt = 0; jt < 8; ++jt) {
    int ocol = jt * 16 + r;
    float b = bias[ocol];
#pragma unroll
    for (int g = 0; g < 4; ++g) {
      int orow = row_base + quad * 4 + g;
      if (orow < N) {
        float v = acc[jt][g] + b;
        if (relu) v = fmaxf(v, 0.f);
        if (out32) out32[(size_t)orow * H + ocol] = v;
        if (out16) out16[(size_t)orow * H + ocol] = f2bf(v);
      }
    }
  }
}

extern "C" void kernel_launch(void* const* d_in, const int* in_sizes, int n_in,
                              void* d_out, int out_size, void* d_ws, size_t ws_size,
                              hipStream_t stream) {
  const float* emb_user = (const float*)d_in[0];
  const float* emb_post = (const float*)d_in[1];
  const float* W_l = (const float*)d_in[2];
  const float* b_l = (const float*)d_in[3];
  const float* W_r = (const float*)d_in[4];
  const int* ev_s = (const int*)d_in[5];
  const int* ev_d = (const int*)d_in[6];
  const int* el_s = (const int*)d_in[7];
  const int* el_d = (const int*)d_in[8];

  const int NU = in_sizes[0] / H;
  const int NP = in_sizes[1] / H;
  const int EV = in_sizes[5];
  const int EL = in_sizes[7];
  const int T = 2 * NP + 2 * NU;
  const size_t NUH = (size_t)NU * H, NPH = (size_t)NP * H;

  // workspace carve (256B-aligned bumps)
  char* p = (char*)d_ws;
  auto alloc = [&](size_t bytes) -> void* {
    void* q = (void*)p; p += (bytes + 255) & ~(size_t)255; return q;
  };
  int*   cnt   = (int*)alloc((size_t)T * 4);
  int*   cur   = (int*)alloc((size_t)T * 4);
  int*   off   = (int*)alloc((size_t)T * 4);
  int*   bsums = (int*)alloc(4 * 256 * 4);
  float* rcp   = (float*)alloc((size_t)T * 4);
  int*   sV_p  = (int*)alloc((size_t)EV * 4);
  int*   sV_u  = (int*)alloc((size_t)EV * 4);
  int*   sL_p  = (int*)alloc((size_t)EL * 4);
  int*   sL_u  = (int*)alloc((size_t)EL * 4);
  short* Wbf   = (short*)alloc((size_t)4 * 3 * 16384 * 2);
  float* bc    = (float*)alloc(4 * H * 4);
  short* xbf_u  = (short*)alloc(NUH * 2);
  short* xbf_p  = (short*)alloc(NPH * 2);
  short* xbf1_u = (short*)alloc(NUH * 2);
  short* xbf1_p = (short*)alloc(NPH * 2);
  short* mV     = (short*)alloc(NPH * 2);   // sized for posts, reused for users
  short* mL     = (short*)alloc(NPH * 2);

  float* out_u_final = (float*)d_out;
  float* out_p_final = (float*)d_out + NUH;

  // count-array index order: {V_p:0, L_p:NP, V_u:2NP, L_u:2NP+NU}
  const int oV_p = 0, oL_p = NP, oV_u = 2 * NP, oL_u = 2 * NP + NU;

  hipMemsetAsync(cnt, 0, (size_t)T * 4, stream);
  hipMemsetAsync(cur, 0, (size_t)T * 4, stream);
  count_edges<<<(EV + 255) / 256, 256, 0, stream>>>(ev_s, ev_d, EV, cnt + oV_u, cnt + oV_p);
  count_edges<<<(EL + 255) / 256, 256, 0, stream>>>(el_s, el_d, EL, cnt + oL_u, cnt + oL_p);
  rcp_from_cnt<<<(T + 255) / 256, 256, 0, stream>>>(cnt, rcp, T);

  int4 starts = { oV_p, oL_p, oV_u, oL_u };
  int4 lens   = { NP, NP, NU, NU };
  int maxb = ((NP > NU ? NP : NU) + 1023) / 1024;
  dim3 gscan(maxb, 4, 1);
  scan_k1<<<gscan, 256, 0, stream>>>(cnt, off, bsums, starts, lens);
  scan_k2<<<4, 256, 0, stream>>>(bsums, lens);
  scan_k3<<<gscan, 256, 0, stream>>>(off, bsums, starts, lens);

  fill_csr<<<(EV + 255) / 256, 256, 0, stream>>>(ev_s, ev_d, EV,
                                                 off + oV_p, cur + oV_p, sV_p,
                                                 off + oV_u, cur + oV_u, sV_u);
  fill_csr<<<(EL + 255) / 256, 256, 0, stream>>>(el_s, el_d, EL,
                                                 off + oL_p, cur + oL_p, sL_p,
                                                 off + oL_u, cur + oL_u, sL_u);

  cvt_bf16<<<((int)(NUH / 4) + 255) / 256, 256, 0, stream>>>(emb_user, xbf_u, (int)NUH);
  cvt_bf16<<<((int)(NPH / 4) + 255) / 256, 256, 0, stream>>>(emb_post, xbf_p, (int)NPH);
  prep_weights<<<(4 * 16384 + 255) / 256, 256, 0, stream>>>(W_l, b_l, W_r, Wbf, bc);

  for (int l = 0; l < 2; ++l) {
    const short* xu = l ? xbf1_u : xbf_u;
    const short* xp = l ? xbf1_p : xbf_p;
    const short* Wpost = Wbf + (size_t)(l * 2 + 0) * 3 * 16384;
    const short* Wuser = Wbf + (size_t)(l * 2 + 1) * 3 * 16384;
    const float* bpost = bc + (l * 2 + 0) * H;
    const float* buser = bc + (l * 2 + 1) * H;

    // posts: mean over incoming users (viewed, liked), then fused transform
    aggregate<<<(NP * 16 + 255) / 256, 256, 0, stream>>>(
        (const bf16x8*)xu, sV_p, off + oV_p, cnt + oV_p, rcp + oV_p,
        sL_p, off + oL_p, cnt + oL_p, rcp + oL_p,
        (bf16x8*)mV, (bf16x8*)mL, NP);
    fused_gemm<<<(NP + 63) / 64, 256, 0, stream>>>(
        mV, mL, xp, Wpost, bpost,
        l ? out_p_final : nullptr, l ? nullptr : xbf1_p, NP, l == 0);

    // users: mean over incoming posts (rev_viewed, rev_liked), then fused transform
    aggregate<<<(NU * 16 + 255) / 256, 256, 0, stream>>>(
        (const bf16x8*)xp, sV_u, off + oV_u, cnt + oV_u, rcp + oV_u,
        sL_u, off + oL_u, cnt + oL_u, rcp + oL_u,
        (bf16x8*)mV, (bf16x8*)mL, NU);
    fused_gemm<<<(NU + 63) / 64, 256, 0, stream>>>(
        mV, mL, xu, Wuser, buser,
        l ? out_u_final : nullptr, l ? nullptr : xbf1_u, NU, l == 0);
  }
}

// Round 3
// 951.731 us; speedup vs baseline: 5.6415x; 1.1943x over previous
//
#include <hip/hip_runtime.h>
#include <hip/hip_bf16.h>

#define H 128

using bf16x8  = __attribute__((ext_vector_type(8))) short;  // 8 bf16 = 4 VGPRs
using floatx4 = __attribute__((ext_vector_type(4))) float;

static __device__ __forceinline__ short f2bf(float f) {
  union { float f; unsigned u; } v; v.f = f;
  unsigned r = v.u + 0x7fffu + ((v.u >> 16) & 1u);  // RNE
  return (short)(r >> 16);
}
static __device__ __forceinline__ float bf2f(short s) {
  union { unsigned u; float f; } v; v.u = ((unsigned)(unsigned short)s) << 16;
  return v.f;
}

// ---- degree counts (int) ----
__global__ void count_edges(const int* __restrict__ src, const int* __restrict__ dst,
                            int E, int* __restrict__ cnt_s, int* __restrict__ cnt_d) {
  int e = blockIdx.x * blockDim.x + threadIdx.x;
  if (e >= E) return;
  atomicAdd(&cnt_s[src[e]], 1);
  atomicAdd(&cnt_d[dst[e]], 1);
}

__global__ void rcp_from_cnt(const int* __restrict__ cnt, float* __restrict__ r, int n) {
  int i = blockIdx.x * blockDim.x + threadIdx.x;
  if (i < n) r[i] = 1.0f / fmaxf((float)cnt[i], 1.0f);
}

// ---- 3-kernel exclusive scan over 4 contiguous count arrays ----
__global__ __launch_bounds__(256) void scan_k1(const int* __restrict__ cnt, int* __restrict__ off,
                                               int* __restrict__ bsums, int4 starts, int4 lens) {
  int a = blockIdx.y;
  int start = ((const int*)&starts)[a];
  int len   = ((const int*)&lens)[a];
  int chunk = blockIdx.x * 1024;
  if (chunk >= len) return;
  const int* in = cnt + start;
  int* out = off + start;
  int tid = threadIdx.x;
  int base = chunk + tid * 4;
  int v[4];
#pragma unroll
  for (int j = 0; j < 4; ++j) v[j] = (base + j < len) ? in[base + j] : 0;
  int s = v[0] + v[1] + v[2] + v[3];
  __shared__ int lds[256];
  lds[tid] = s; __syncthreads();
  for (int o = 1; o < 256; o <<= 1) {
    int t = (tid >= o) ? lds[tid - o] : 0;
    __syncthreads();
    lds[tid] += t;
    __syncthreads();
  }
  int run = lds[tid] - s;  // exclusive prefix of this thread's 4
#pragma unroll
  for (int j = 0; j < 4; ++j) { if (base + j < len) out[base + j] = run; run += v[j]; }
  if (tid == 255) bsums[a * 256 + blockIdx.x] = lds[255];
}

__global__ __launch_bounds__(256) void scan_k2(int* __restrict__ bsums, int4 lens) {
  int a = blockIdx.x;
  int len = ((const int*)&lens)[a];
  int nb = (len + 1023) >> 10;
  int tid = threadIdx.x;
  int s = (tid < nb) ? bsums[a * 256 + tid] : 0;  // guard: slots >= nb are poisoned
  __shared__ int lds[256];
  lds[tid] = s; __syncthreads();
  for (int o = 1; o < 256; o <<= 1) {
    int t = (tid >= o) ? lds[tid - o] : 0;
    __syncthreads();
    lds[tid] += t;
    __syncthreads();
  }
  bsums[a * 256 + tid] = lds[tid] - s;
}

__global__ __launch_bounds__(256) void scan_k3(int* __restrict__ off, const int* __restrict__ bsums,
                                               int4 starts, int4 lens) {
  int a = blockIdx.y;
  int start = ((const int*)&starts)[a];
  int len   = ((const int*)&lens)[a];
  int chunk = blockIdx.x * 1024;
  if (chunk >= len) return;
  int add = bsums[a * 256 + blockIdx.x];
  int* out = off + start;
  int base = chunk + threadIdx.x * 4;
#pragma unroll
  for (int j = 0; j < 4; ++j) if (base + j < len) out[base + j] += add;
}

// ---- CSR fill (both directions of one relation) ----
__global__ void fill_csr(const int* __restrict__ src, const int* __restrict__ dst, int E,
                         const int* __restrict__ off_d, int* __restrict__ cur_d, int* __restrict__ sort_d,
                         const int* __restrict__ off_s, int* __restrict__ cur_s, int* __restrict__ sort_s) {
  int e = blockIdx.x * blockDim.x + threadIdx.x;
  if (e >= E) return;
  int s = src[e], d = dst[e];
  sort_d[off_d[d] + atomicAdd(&cur_d[d], 1)] = s;  // neighbors of dst node (src ids)
  sort_s[off_s[s] + atomicAdd(&cur_s[s], 1)] = d;  // neighbors of src node (dst ids)
}

// ---- fp32 -> bf16 streaming convert ----
__global__ void cvt_bf16(const float* __restrict__ in, short* __restrict__ out, int n) {
  int idx = (blockIdx.x * blockDim.x + threadIdx.x) * 4;
  if (idx >= n) return;
  float4 v = *(const float4*)(in + idx);
  short4 o = { f2bf(v.x), f2bf(v.y), f2bf(v.z), f2bf(v.w) };
  *(short4*)(out + idx) = o;
}

// ---- weight prep: bf16 convert, combine Wr pair and bias pair per (layer,type) ----
__global__ void prep_weights(const float* __restrict__ W_l, const float* __restrict__ b_l,
                             const float* __restrict__ W_r,
                             short* __restrict__ Wbf, float* __restrict__ bc) {
  int i = blockIdx.x * blockDim.x + threadIdx.x;
  if (i >= 4 * 16384) return;
  int s = i >> 14, e = i & 16383;
  int l = s >> 1, t = s & 1;
  int rA = t ? 1 : 0, rB = t ? 3 : 2;
  const float* WA = W_l + ((size_t)(l * 4 + rA) << 14);
  const float* WB = W_l + ((size_t)(l * 4 + rB) << 14);
  const float* RA = W_r + ((size_t)(l * 4 + rA) << 14);
  const float* RB = W_r + ((size_t)(l * 4 + rB) << 14);
  short* o = Wbf + (size_t)s * 3 * 16384;
  o[e]             = f2bf(WA[e]);
  o[16384 + e]     = f2bf(WB[e]);
  o[2 * 16384 + e] = f2bf(RA[e] + RB[e]);
  if (e < H) bc[s * H + e] = b_l[(l * 4 + rA) * H + e] + b_l[(l * 4 + rB) * H + e];
}

// ---- gather-based segment mean: 16 lanes per node, bf16x8 per lane, fp32 accum ----
__global__ __launch_bounds__(256) void aggregate(
    const bf16x8* __restrict__ xbf,
    const int* __restrict__ sV, const int* __restrict__ offV, const int* __restrict__ cntV,
    const float* __restrict__ rV,
    const int* __restrict__ sL, const int* __restrict__ offL, const int* __restrict__ cntL,
    const float* __restrict__ rL,
    bf16x8* __restrict__ mV, bf16x8* __restrict__ mL, int N) {
  int t = blockIdx.x * 256 + threadIdx.x;
  int node = t >> 4, c = t & 15;
  if (node >= N) return;
  float acc[8];
  {
    int o = offV[node], n = cntV[node];
#pragma unroll
    for (int j = 0; j < 8; ++j) acc[j] = 0.f;
    for (int i = o; i < o + n; ++i) {
      bf16x8 v = xbf[(size_t)sV[i] * 16 + c];
#pragma unroll
      for (int j = 0; j < 8; ++j) acc[j] += bf2f(v[j]);
    }
    float r = rV[node];
    bf16x8 w;
#pragma unroll
    for (int j = 0; j < 8; ++j) w[j] = f2bf(acc[j] * r);
    mV[(size_t)node * 16 + c] = w;
  }
  {
    int o = offL[node], n = cntL[node];
#pragma unroll
    for (int j = 0; j < 8; ++j) acc[j] = 0.f;
    for (int i = o; i < o + n; ++i) {
      bf16x8 v = xbf[(size_t)sL[i] * 16 + c];
#pragma unroll
      for (int j = 0; j < 8; ++j) acc[j] += bf2f(v[j]);
    }
    float r = rL[node];
    bf16x8 w;
#pragma unroll
    for (int j = 0; j < 8; ++j) w[j] = f2bf(acc[j] * r);
    mL[(size_t)node * 16 + c] = w;
  }
}

// ---- fused SAGE transform: out = mV@WA.T + mL@WB.T + x@WRc.T + b [, ReLU]
// Block = 4 waves x 256 rows (4 row-tiles of 16 per wave). Weights staged per-mat
// into 32 KB LDS in pre-swizzled fragment order -> conflict-free ds_read_b128,
// B-frag read shared across 4 row-tiles; weight global traffic amortized 16x vs R2.
// A frag: A[m=lane&15][k=quad*8+j]; B frag: B[k][n=lane&15]=W[n][k]; C/D: col=lane&15, row=quad*4+reg.
__global__ __launch_bounds__(256) void fused_gemm(
    const short* __restrict__ mV, const short* __restrict__ mL, const short* __restrict__ xb,
    const short* __restrict__ Wset, const float* __restrict__ bias,
    float* __restrict__ out32, short* __restrict__ out16, int N, int relu) {
  __shared__ short Wlds[2048 * 8];  // 32 KB: chunk c=( (jt*4+kkI)*64 + lane ), 16 B each
  int tid = threadIdx.x;
  int wave = tid >> 6, lane = tid & 63;
  int r = lane & 15, quad = lane >> 4;
  int row_base = blockIdx.x * 256 + wave * 64;

  const short* mats[3] = { mV, mL, xb };
  floatx4 acc[4][8];
#pragma unroll
  for (int t = 0; t < 4; ++t)
#pragma unroll
    for (int j = 0; j < 8; ++j) acc[t][j] = floatx4{0.f, 0.f, 0.f, 0.f};

  for (int m = 0; m < 3; ++m) {
    const short* W = Wset + (size_t)m * 16384;
    // stage: 2048 x 16B chunks; chunk c holds the B-frag lane (c&63) needs for (jt,kkI)=(c>>8, (c>>6)&3)
#pragma unroll
    for (int it = 0; it < 8; ++it) {
      int c = it * 256 + tid;
      int cl = c & 63;
      int kj = c >> 6;          // 0..31
      int jt = kj >> 2, kkI = kj & 3;
      int rr = cl & 15, qq = cl >> 4;
      bf16x8 v = *(const bf16x8*)(W + (jt * 16 + rr) * H + kkI * 32 + qq * 8);
      *(bf16x8*)(Wlds + (size_t)c * 8) = v;
    }
    __syncthreads();

#pragma unroll
    for (int kkI = 0; kkI < 4; ++kkI) {
      bf16x8 af[4];
#pragma unroll
      for (int t = 0; t < 4; ++t) {
        int row = row_base + t * 16 + r;
        int rowc = row < N ? row : N - 1;
        af[t] = *(const bf16x8*)(mats[m] + (size_t)rowc * H + kkI * 32 + quad * 8);
      }
#pragma unroll
      for (int jt = 0; jt < 8; ++jt) {
        bf16x8 bf = *(const bf16x8*)(Wlds + ((size_t)((jt * 4 + kkI) * 64 + lane)) * 8);
#pragma unroll
        for (int t = 0; t < 4; ++t)
          acc[t][jt] = __builtin_amdgcn_mfma_f32_16x16x32_bf16(af[t], bf, acc[t][jt], 0, 0, 0);
      }
    }
    __syncthreads();
  }

#pragma unroll
  for (int t = 0; t < 4; ++t) {
#pragma unroll
    for (int jt = 0; jt < 8; ++jt) {
      int ocol = jt * 16 + r;
      float b = bias[ocol];
#pragma unroll
      for (int g = 0; g < 4; ++g) {
        int orow = row_base + t * 16 + quad * 4 + g;
        if (orow < N) {
          float v = acc[t][jt][g] + b;
          if (relu) v = fmaxf(v, 0.f);
          if (out32) out32[(size_t)orow * H + ocol] = v;
          if (out16) out16[(size_t)orow * H + ocol] = f2bf(v);
        }
      }
    }
  }
}

extern "C" void kernel_launch(void* const* d_in, const int* in_sizes, int n_in,
                              void* d_out, int out_size, void* d_ws, size_t ws_size,
                              hipStream_t stream) {
  const float* emb_user = (const float*)d_in[0];
  const float* emb_post = (const float*)d_in[1];
  const float* W_l = (const float*)d_in[2];
  const float* b_l = (const float*)d_in[3];
  const float* W_r = (const float*)d_in[4];
  const int* ev_s = (const int*)d_in[5];
  const int* ev_d = (const int*)d_in[6];
  const int* el_s = (const int*)d_in[7];
  const int* el_d = (const int*)d_in[8];

  const int NU = in_sizes[0] / H;
  const int NP = in_sizes[1] / H;
  const int EV = in_sizes[5];
  const int EL = in_sizes[7];
  const int T = 2 * NP + 2 * NU;
  const size_t NUH = (size_t)NU * H, NPH = (size_t)NP * H;

  // workspace carve (256B-aligned bumps)
  char* p = (char*)d_ws;
  auto alloc = [&](size_t bytes) -> void* {
    void* q = (void*)p; p += (bytes + 255) & ~(size_t)255; return q;
  };
  int*   cnt   = (int*)alloc((size_t)T * 4);
  int*   cur   = (int*)alloc((size_t)T * 4);
  int*   off   = (int*)alloc((size_t)T * 4);
  int*   bsums = (int*)alloc(4 * 256 * 4);
  float* rcp   = (float*)alloc((size_t)T * 4);
  int*   sV_p  = (int*)alloc((size_t)EV * 4);
  int*   sV_u  = (int*)alloc((size_t)EV * 4);
  int*   sL_p  = (int*)alloc((size_t)EL * 4);
  int*   sL_u  = (int*)alloc((size_t)EL * 4);
  short* Wbf   = (short*)alloc((size_t)4 * 3 * 16384 * 2);
  float* bc    = (float*)alloc(4 * H * 4);
  short* xbf_u  = (short*)alloc(NUH * 2);
  short* xbf_p  = (short*)alloc(NPH * 2);
  short* xbf1_u = (short*)alloc(NUH * 2);
  short* xbf1_p = (short*)alloc(NPH * 2);
  short* mV     = (short*)alloc(NPH * 2);   // sized for posts, reused for users
  short* mL     = (short*)alloc(NPH * 2);

  float* out_u_final = (float*)d_out;
  float* out_p_final = (float*)d_out + NUH;

  // count-array index order: {V_p:0, L_p:NP, V_u:2NP, L_u:2NP+NU}
  const int oV_p = 0, oL_p = NP, oV_u = 2 * NP, oL_u = 2 * NP + NU;

  hipMemsetAsync(cnt, 0, (size_t)T * 4, stream);
  hipMemsetAsync(cur, 0, (size_t)T * 4, stream);
  count_edges<<<(EV + 255) / 256, 256, 0, stream>>>(ev_s, ev_d, EV, cnt + oV_u, cnt + oV_p);
  count_edges<<<(EL + 255) / 256, 256, 0, stream>>>(el_s, el_d, EL, cnt + oL_u, cnt + oL_p);
  rcp_from_cnt<<<(T + 255) / 256, 256, 0, stream>>>(cnt, rcp, T);

  int4 starts = { oV_p, oL_p, oV_u, oL_u };
  int4 lens   = { NP, NP, NU, NU };
  int maxb = ((NP > NU ? NP : NU) + 1023) / 1024;
  dim3 gscan(maxb, 4, 1);
  scan_k1<<<gscan, 256, 0, stream>>>(cnt, off, bsums, starts, lens);
  scan_k2<<<4, 256, 0, stream>>>(bsums, lens);
  scan_k3<<<gscan, 256, 0, stream>>>(off, bsums, starts, lens);

  fill_csr<<<(EV + 255) / 256, 256, 0, stream>>>(ev_s, ev_d, EV,
                                                 off + oV_p, cur + oV_p, sV_p,
                                                 off + oV_u, cur + oV_u, sV_u);
  fill_csr<<<(EL + 255) / 256, 256, 0, stream>>>(el_s, el_d, EL,
                                                 off + oL_p, cur + oL_p, sL_p,
                                                 off + oL_u, cur + oL_u, sL_u);

  cvt_bf16<<<((int)(NUH / 4) + 255) / 256, 256, 0, stream>>>(emb_user, xbf_u, (int)NUH);
  cvt_bf16<<<((int)(NPH / 4) + 255) / 256, 256, 0, stream>>>(emb_post, xbf_p, (int)NPH);
  prep_weights<<<(4 * 16384 + 255) / 256, 256, 0, stream>>>(W_l, b_l, W_r, Wbf, bc);

  for (int l = 0; l < 2; ++l) {
    const short* xu = l ? xbf1_u : xbf_u;
    const short* xp = l ? xbf1_p : xbf_p;
    const short* Wpost = Wbf + (size_t)(l * 2 + 0) * 3 * 16384;
    const short* Wuser = Wbf + (size_t)(l * 2 + 1) * 3 * 16384;
    const float* bpost = bc + (l * 2 + 0) * H;
    const float* buser = bc + (l * 2 + 1) * H;

    // posts: mean over incoming users (viewed, liked), then fused transform
    aggregate<<<(NP * 16 + 255) / 256, 256, 0, stream>>>(
        (const bf16x8*)xu, sV_p, off + oV_p, cnt + oV_p, rcp + oV_p,
        sL_p, off + oL_p, cnt + oL_p, rcp + oL_p,
        (bf16x8*)mV, (bf16x8*)mL, NP);
    fused_gemm<<<(NP + 255) / 256, 256, 0, stream>>>(
        mV, mL, xp, Wpost, bpost,
        l ? out_p_final : nullptr, l ? nullptr : xbf1_p, NP, l == 0);

    // users: mean over incoming posts (rev_viewed, rev_liked), then fused transform
    aggregate<<<(NU * 16 + 255) / 256, 256, 0, stream>>>(
        (const bf16x8*)xp, sV_u, off + oV_u, cnt + oV_u, rcp + oV_u,
        sL_u, off + oL_u, cnt + oL_u, rcp + oL_u,
        (bf16x8*)mV, (bf16x8*)mL, NU);
    fused_gemm<<<(NU + 255) / 256, 256, 0, stream>>>(
        mV, mL, xu, Wuser, buser,
        l ? out_u_final : nullptr, l ? nullptr : xbf1_u, NU, l == 0);
  }
}